// Round 17
// baseline (119.369 us; speedup 1.0000x reference)
//
#include <hip/hip_runtime.h>

#define TT 16384
#define DD 2048
#define EE 64

typedef __attribute__((ext_vector_type(8))) short bf16x8;
typedef __attribute__((ext_vector_type(8))) unsigned short ushort8;
typedef __attribute__((ext_vector_type(4))) float f32x4;
typedef __attribute__((ext_vector_type(16))) float f32x16;

__device__ __forceinline__ unsigned short bf16_rne(float f) {
    unsigned u = __float_as_uint(f);
    return (unsigned short)((u + 0x7FFFu + ((u >> 16) & 1u)) >> 16);
}
__device__ __forceinline__ float bf16_f32(unsigned short h) {
    return __uint_as_float(((unsigned)h) << 16);
}
__device__ __forceinline__ unsigned cvt_pk(float lo, float hi) {
    unsigned r;
    asm("v_cvt_pk_bf16_f32 %0, %1, %2" : "=v"(r) : "v"(lo), "v"(hi));
    return r;
}
__device__ __forceinline__ bf16x8 pack4(unsigned a, unsigned b, unsigned c, unsigned d) {
    union { unsigned u[4]; bf16x8 v; } t;
    t.u[0] = a; t.u[1] = b; t.u[2] = c; t.u[3] = d;
    return t.v;
}
__device__ __forceinline__ void gload16(void* lds, const void* g) {
    __builtin_amdgcn_global_load_lds(
        (const __attribute__((address_space(1))) unsigned int*)g,
        (__attribute__((address_space(3))) unsigned int*)lds, 16, 0, 0);
}
#define SB0() __builtin_amdgcn_sched_barrier(0)

// ---------------------------------------------------------------------------
// W [2048][64] f32 -> wpack: 32x32x16 A-fragments per 16-k chunk t=0..127.
// frag_id = t*4 + m*2 + h ; wpack[frag_id*512 + lane*8 + j] = bf16(hi/lo) of
//   wg[(t*16 + (lane>>5)*8 + j)*64 + m*32 + (lane&31)]      (verified R6/R7)
__global__ __launch_bounds__(256)
void wconv(const float* __restrict__ wg, unsigned short* __restrict__ wpack) {
    const int g = (int)blockIdx.x * 256 + threadIdx.x;  // 32768 threads
    const int t = g >> 8, m = (g >> 7) & 1, h = (g >> 6) & 1, lane = g & 63;
    const int e = m * 32 + (lane & 31);
    const int ks = t * 16 + (lane >> 5) * 8;
    ushort8 v;
#pragma unroll
    for (int j = 0; j < 8; ++j) {
        const float f = wg[(size_t)(ks + j) * EE + e];
        const unsigned short hi = bf16_rne(f);
        v[j] = h ? bf16_rne(f - bf16_f32(hi)) : hi;
    }
    *(ushort8*)(wpack + (size_t)g * 8) = v;
}

// ---------------------------------------------------------------------------
// Fused gate GEMM, 64 TOKENS PER WAVE (2 x 32-token B-tiles sharing one set
// of W A-fragments -> W L2 traffic 512->128 MB).  Block = 512 thr = 8 waves
// on the same 64 tokens; wave q owns K-eighth [q*256,+256), 16 steps x 16 k.
// Per-wave-private 2-slot LDS ring; per-wave counted vmcnt, no K-loop
// barriers.  Grid 256 = 1 block/CU.
// R16 bug fixed: tail clobbered W14 (loadW(15,WA)) and computed step 14
// with the dead W13 (compute(slotA,WB)).  Now: loadW(15,WB); step14 uses WA.
__global__ __launch_bounds__(512, 2)
void gate_fused(const float* __restrict__ x, const unsigned short* __restrict__ wpack,
                const float* __restrict__ loads, float* __restrict__ out,
                float* __restrict__ binpart) {
    __shared__ __align__(16) float arena[16384];  // 64 KB: 8 waves x 2 x 1024 f
    __shared__ float bins[64];

    const int tid = threadIdx.x, lane = tid & 63, q = tid >> 6;  // K-eighth
    const int tb = (int)blockIdx.x;
    const int tok32 = lane & 31, hi5 = lane >> 5;

    f32x16 acc[4];  // [tile*2 + m]
#pragma unroll
    for (int a = 0; a < 4; ++a)
#pragma unroll
        for (int r = 0; r < 16; ++r) acc[a][r] = 0.0f;

    float* slotA = arena + (size_t)q * 2048;
    float* slotB = slotA + 1024;

    // stage step s (64 rows x 16 k = 4 KB) into slot: 4 x gload16.
    // instr i covers rows i*16..i*16+15 (rowp=lane>>2), 64-B row segments,
    // chunk swizzle c=(lane&3)^(rowp&3) pre-applied on the SOURCE (rule 21).
    auto stage_x = [&](int s, float* sb) {
#pragma unroll
        for (int i = 0; i < 4; ++i) {
            const int rowp = lane >> 2;
            const int r = i * 16 + rowp;
            const int c = (lane & 3) ^ (rowp & 3);
            gload16(sb + i * 256,
                    x + (size_t)(tb * 64 + r) * DD + q * 256 + s * 16 + c * 4);
        }
    };
    // 4 W frags (m0h,m0l,m1h,m1l) for global chunk q*16+s
    auto loadW = [&](int s, bf16x8 (&W)[4]) {
        const unsigned short* base =
            wpack + ((size_t)(q * 16 + s) * 4) * 512 + lane * 8;
#pragma unroll
        for (int f = 0; f < 4; ++f)
            W[f] = *(const bf16x8*)(base + (size_t)f * 512);
    };
    auto compute = [&](const float* sb, bf16x8 (&W)[4]) {
        bf16x8 bhi[2], blo[2];
#pragma unroll
        for (int t = 0; t < 2; ++t) {
            const int r = t * 32 + tok32;
            const int i = r >> 4, rowp = r & 15;
            const int u0 = hi5 * 2;
            const f32x4 va = *(const f32x4*)(sb + i * 256 + rowp * 16 +
                                             ((u0) ^ (rowp & 3)) * 4);
            const f32x4 vb = *(const f32x4*)(sb + i * 256 + rowp * 16 +
                                             ((u0 + 1) ^ (rowp & 3)) * 4);
            const float cf[8] = {va.x, va.y, va.z, va.w, vb.x, vb.y, vb.z, vb.w};
            unsigned ph[4], pl[4];
#pragma unroll
            for (int j = 0; j < 4; ++j) {
                ph[j] = cvt_pk(cf[2 * j], cf[2 * j + 1]);
                const float h0 = __uint_as_float(ph[j] << 16);
                const float h1 = __uint_as_float(ph[j] & 0xFFFF0000u);
                pl[j] = cvt_pk(cf[2 * j] - h0, cf[2 * j + 1] - h1);
            }
            bhi[t] = pack4(ph[0], ph[1], ph[2], ph[3]);
            blo[t] = pack4(pl[0], pl[1], pl[2], pl[3]);
        }
#pragma unroll
        for (int m = 0; m < 2; ++m)
#pragma unroll
            for (int t = 0; t < 2; ++t) {
                acc[t * 2 + m] = __builtin_amdgcn_mfma_f32_32x32x16_bf16(
                    W[m * 2], bhi[t], acc[t * 2 + m], 0, 0, 0);
                acc[t * 2 + m] = __builtin_amdgcn_mfma_f32_32x32x16_bf16(
                    W[m * 2], blo[t], acc[t * 2 + m], 0, 0, 0);
                acc[t * 2 + m] = __builtin_amdgcn_mfma_f32_32x32x16_bf16(
                    W[m * 2 + 1], bhi[t], acc[t * 2 + m], 0, 0, 0);
            }
    };

    bf16x8 WA[4], WB[4];
    // prologue FIFO: st0(4) W0(4) st1(4) = 12; vmcnt(8) drains st0; the
    // compiler's W0-register wait (vmcnt(4)) drains W0, keeps st1.
    stage_x(0, slotA); SB0();
    loadW(0, WA); SB0();
    stage_x(1, slotB); SB0();
    asm volatile("s_waitcnt vmcnt(8)" ::: "memory");
    SB0();

#pragma unroll 1
    for (int s = 0; s < 14; ++s) {
        if (s & 1) loadW(s + 1, WA); else loadW(s + 1, WB);
        SB0();
        compute((s & 1) ? slotB : slotA, (s & 1) ? WB : WA);
        SB0();
        stage_x(s + 2, (s & 1) ? slotB : slotA);  // after reads of this slot
        SB0();
        // FIFO: st(s+1)4, W(s+1)4, st(s+2)4 -> drain st(s+1); compiler's
        // W(s+1)-reg wait before next compute keeps st(s+2) in flight.
        asm volatile("s_waitcnt vmcnt(8)" ::: "memory");
        SB0();
    }
    // after s=13: WA = W14 (loaded at s=13), slotA = st14, outstanding
    // {W14(4 drained by compiler), st15(4)}.  W13 in WB is dead.
    loadW(15, WB); SB0();                              // W15 -> WB
    compute(slotA, WA);                                // step 14 with W14
    SB0();
    asm volatile("s_waitcnt vmcnt(4)" ::: "memory");   // drain st15, keep W15
    SB0();
    compute(slotB, WB);                                // step 15 with W15

    // ---- 8-way K reduce, two passes (tile0 then tile1), stride 36 --------
    __syncthreads();
#pragma unroll 1
    for (int pass = 0; pass < 2; ++pass) {
        if (q != 0) {
            float* p = arena + (size_t)(q - 1) * 2304 + lane * 36;
#pragma unroll
            for (int a = 0; a < 2; ++a)
#pragma unroll
                for (int pp = 0; pp < 4; ++pp) {
                    const f32x16& A = acc[pass * 2 + a];
                    const f32x4 t_ = {A[pp * 4], A[pp * 4 + 1],
                                      A[pp * 4 + 2], A[pp * 4 + 3]};
                    *(f32x4*)(p + a * 16 + pp * 4) = t_;
                }
        }
        __syncthreads();
        if (q == 0) {
#pragma unroll 1
            for (int qq = 0; qq < 7; ++qq) {
                const float* p = arena + (size_t)qq * 2304 + lane * 36;
#pragma unroll
                for (int a = 0; a < 2; ++a)
#pragma unroll
                    for (int pp = 0; pp < 4; ++pp) {
                        const f32x4 t_ = *(const f32x4*)(p + a * 16 + pp * 4);
#pragma unroll
                        for (int j = 0; j < 4; ++j)
                            acc[pass * 2 + a][pp * 4 + j] += t_[j];
                    }
            }
        }
        __syncthreads();
    }
    if (q != 0) return;

    // ---- top-2 per tile: lane holds e = m*32 + (r&3) + 8*(r>>2) + 4*hi5 --
    bins[lane] = 0.0f;
#pragma unroll 1
    for (int t = 0; t < 2; ++t) {
        float v1 = -3.4e38f, u1 = 0.0f, v2 = -3.4e38f, u2 = 0.0f;
        int i1 = 0x7fffffff, i2 = 0x7fffffff;
#pragma unroll
        for (int m = 0; m < 2; ++m)
#pragma unroll
            for (int r = 0; r < 16; ++r) {
                const int e = m * 32 + (r & 3) + 8 * (r >> 2) + 4 * hi5;
                const float u = acc[t * 2 + m][r];
                const float b = u - (loads[e] - 0.015625f) * 2.0f;
                if ((b > v1) || (b == v1 && e < i1)) {
                    v2 = v1; u2 = u1; i2 = i1;
                    v1 = b;  u1 = u;  i1 = e;
                } else if ((b > v2) || (b == v2 && e < i2)) {
                    v2 = b; u2 = u; i2 = e;
                }
            }
        {   // merge lane <-> lane+32 (same token, complementary expert rows)
            const float ov1 = __shfl_xor(v1, 32), ou1 = __shfl_xor(u1, 32);
            const float ov2 = __shfl_xor(v2, 32), ou2 = __shfl_xor(u2, 32);
            const int oi1 = __shfl_xor(i1, 32), oi2 = __shfl_xor(i2, 32);
            if ((ov1 > v1) || (ov1 == v1 && oi1 < i1)) {
                if ((v1 > ov2) || (v1 == ov2 && i1 < oi2)) { v2 = v1; u2 = u1; i2 = i1; }
                else                                        { v2 = ov2; u2 = ou2; i2 = oi2; }
                v1 = ov1; u1 = ou1; i1 = oi1;
            } else if ((ov1 > v2) || (ov1 == v2 && oi1 < i2)) {
                v2 = ov1; u2 = ou1; i2 = oi1;
            }
        }
        if (lane < 32) {
            const int tok = tb * 64 + t * 32 + tok32;
            const float mx = fmaxf(u1, u2);
            const float e1 = __expf(u1 - mx), e2 = __expf(u2 - mx);
            const float w1 = e1 / (e1 + e2), w2 = e2 / (e1 + e2);
            *(float2*)(out + 2 * tok) = make_float2(w1, w2);
            *(float2*)(out + 2 * TT + 2 * tok) = make_float2((float)i1, (float)i2);
            atomicAdd(&bins[i1], w1);
            atomicAdd(&bins[i2], w2);
        }
    }
    binpart[(size_t)tb * 64 + lane] = bins[lane];
}

// ---------------------------------------------------------------------------
// Merged finalize: 1 block x 256 thr sums [256][64] rows (fixed order) + EMA.
__global__ __launch_bounds__(256)
void finalize(const float* __restrict__ binpart, const float* __restrict__ loads,
              float* __restrict__ out) {
    __shared__ float p[4][64];
    const int e = threadIdx.x & 63, sub = threadIdx.x >> 6;  // 0..3
    float s = 0.0f;
#pragma unroll 8
    for (int r = 0; r < 64; ++r)
        s += binpart[(size_t)(sub * 64 + r) * 64 + e];
    p[sub][e] = s;
    __syncthreads();
    if (sub == 0) {
        const float tot = ((p[0][e] + p[1][e]) + p[2][e]) + p[3][e];
        out[4 * TT + e] = 0.9f * loads[e] + 0.1f * (tot * (1.0f / 16384.0f));
    }
}

// ---------------------------------------------------------------------------
extern "C" void kernel_launch(void* const* d_in, const int* in_sizes, int n_in,
                              void* d_out, int out_size, void* d_ws, size_t ws_size,
                              hipStream_t stream) {
    const float* x = (const float*)d_in[0];      // [16384, 2048]
    const float* wg = (const float*)d_in[1];     // [2048, 64]
    const float* loads = (const float*)d_in[2];  // [64]
    float* out = (float*)d_out;

    unsigned short* wpack = (unsigned short*)d_ws;             // 512 KB
    float* binpart = (float*)(wpack + (size_t)128 * 4 * 512);  // [256][64]

    hipLaunchKernelGGL(wconv, dim3(128), dim3(256), 0, stream, wg, wpack);
    hipLaunchKernelGGL(gate_fused, dim3(256), dim3(512), 0, stream,
                       x, wpack, loads, out, binpart);
    hipLaunchKernelGGL(finalize, dim3(1), dim3(256), 0, stream,
                       binpart, loads, out);
}

// Round 19
// 40.195 us; speedup vs baseline: 2.9698x; 2.9698x over previous
//
#include <hip/hip_runtime.h>

#define TT 16384
#define DD 2048
#define EE 64

typedef __attribute__((ext_vector_type(8))) short bf16x8;
typedef __attribute__((ext_vector_type(8))) unsigned short ushort8;
typedef __attribute__((ext_vector_type(4))) float f32x4;

__device__ __forceinline__ unsigned short bf16_rne(float f) {
    unsigned u = __float_as_uint(f);
    return (unsigned short)((u + 0x7FFFu + ((u >> 16) & 1u)) >> 16);
}
__device__ __forceinline__ float bf16_f32(unsigned short h) {
    return __uint_as_float(((unsigned)h) << 16);
}
__device__ __forceinline__ unsigned cvt_pk(float lo, float hi) {
    unsigned r;
    asm("v_cvt_pk_bf16_f32 %0, %1, %2" : "=v"(r) : "v"(lo), "v"(hi));
    return r;
}
__device__ __forceinline__ bf16x8 pack4(unsigned a, unsigned b, unsigned c, unsigned d) {
    union { unsigned u[4]; bf16x8 v; } t;
    t.u[0] = a; t.u[1] = b; t.u[2] = c; t.u[3] = d;
    return t.v;
}
__device__ __forceinline__ void gload16(void* lds, const void* g) {
    __builtin_amdgcn_global_load_lds(
        (const __attribute__((address_space(1))) unsigned int*)g,
        (__attribute__((address_space(3))) unsigned int*)lds, 16, 0, 0);
}
#define SB0() __builtin_amdgcn_sched_barrier(0)

// ---------------------------------------------------------------------------
// W [2048][64] f32 -> wpack (R5/R13-verified 16x16x32 A-frag layout).
// wpack[K0][h][m][lane][j] = bf16 hi/lo of wg[(K0*32+(lane>>4)*8+j)*64 + m*16+(lane&15)]
__global__ __launch_bounds__(256)
void wconv(const float* __restrict__ wg, unsigned short* __restrict__ wpack) {
    const int t = (int)blockIdx.x * 256 + threadIdx.x;  // 32768 threads
    const int K0 = t >> 9, h = (t >> 8) & 1, m = (t >> 6) & 3, lane = t & 63;
    const int e = m * 16 + (lane & 15);
    const int ks = K0 * 32 + (lane >> 4) * 8;
    ushort8 v;
#pragma unroll
    for (int j = 0; j < 8; ++j) {
        const float f = wg[(size_t)(ks + j) * EE + e];
        const unsigned short hi = bf16_rne(f);
        v[j] = h ? bf16_rne(f - bf16_f32(hi)) : hi;
    }
    *(ushort8*)(wpack + ((size_t)(K0 * 8 + h * 4 + m) * 64 + lane) * 8) = v;
}

// ---------------------------------------------------------------------------
// 32 TOKENS PER WAVE (2 x 16-token B-tiles share one W frag set -> W L2
// traffic 512->256 MB) with the R13-verified 128-B-segment staging geometry.
// Block = 256 thr = 4 waves on the same 32 tokens; wave q owns K-quarter
// [q*512,+512), 16 steps x 32 k.  Staging fully wave-private (3-slot 4 KB
// ring each, 48 KB total) -> NO K-loop barriers.  W: 3 named register sets
// loaded 2 steps ahead.  Steady vmcnt(16) drains exactly {st(s), W(s)}.
// Grid 512 = 2 blocks/CU.  (R18 fix: tail ITERs use nwl=0 so the token
// paste is a valid identifier; DOW=0 folds the call away.)
__global__ __launch_bounds__(256, 2)
void gate_fused(const float* __restrict__ x, const unsigned short* __restrict__ wpack,
                const float* __restrict__ loads, float* __restrict__ out,
                float* __restrict__ binpart) {
    __shared__ __align__(16) float arena[12288];  // 48 KB: 4 waves x 3 x 1024 f
    __shared__ float bins[64];

    const int tid = threadIdx.x, lane = tid & 63, q = tid >> 6;  // K-quarter
    const int tb = (int)blockIdx.x;

    f32x4 a0[4] = {{0,0,0,0},{0,0,0,0},{0,0,0,0},{0,0,0,0}};  // tile 0 (tok 0-15)
    f32x4 a1[4] = {{0,0,0,0},{0,0,0,0},{0,0,0,0},{0,0,0,0}};  // tile 1 (tok 16-31)

    float* ring = arena + (size_t)q * 3072;
    float *sp0 = ring, *sp1 = ring + 1024, *sp2 = ring + 2048;

    // stage step s (32 rows x 32 k = 4 KB): 4 x gload16, 8 rows x 128 B each.
    auto stage_x = [&](int s, float* sb) {
#pragma unroll
        for (int i = 0; i < 4; ++i) {
            const int rowp = lane >> 3;       // 0..7
            const int c = (lane & 7) ^ rowp;  // source-side chunk swizzle
            gload16(sb + i * 256,
                    x + (size_t)(tb * 32 + i * 8 + rowp) * DD + q * 512 + s * 32 + c * 4);
        }
    };
    // 8 W frags for 32-k chunk kc = q*16 + s (hi[4] + lo[4]), 1 KB/frag.
    auto loadW = [&](int s, bf16x8 (&wh)[4], bf16x8 (&wl)[4]) {
        const unsigned short* base = wpack + (size_t)(q * 16 + s) * 4096 + lane * 8;
#pragma unroll
        for (int m = 0; m < 4; ++m) {
            wh[m] = *(const bf16x8*)(base + (size_t)m * 512);
            wl[m] = *(const bf16x8*)(base + (size_t)(4 + m) * 512);
        }
    };
    // read both tiles' B-frags (R13-verified address math; sw identical for
    // r and 16+r since 16 % 8 == 0).
    auto readx = [&](const float* sb, f32x4& va0, f32x4& vb0, f32x4& va1, f32x4& vb1) {
        const int rl = lane & 15;
        const int kgc = (lane >> 4) << 1;
        const int sw = rl & 7;
        va0 = *(const f32x4*)(sb + rl * 32 + ((kgc) ^ sw) * 4);
        vb0 = *(const f32x4*)(sb + rl * 32 + ((kgc + 1) ^ sw) * 4);
        va1 = *(const f32x4*)(sb + (16 + rl) * 32 + ((kgc) ^ sw) * 4);
        vb1 = *(const f32x4*)(sb + (16 + rl) * 32 + ((kgc + 1) ^ sw) * 4);
    };
    auto domfma = [&](const f32x4& va, const f32x4& vb,
                      bf16x8 (&wh)[4], bf16x8 (&wl)[4], f32x4 (&ac)[4]) {
        const float cf[8] = {va.x, va.y, va.z, va.w, vb.x, vb.y, vb.z, vb.w};
        unsigned ph[4], pl[4];
#pragma unroll
        for (int j = 0; j < 4; ++j) {
            ph[j] = cvt_pk(cf[2 * j], cf[2 * j + 1]);
            const float h0 = __uint_as_float(ph[j] << 16);
            const float h1 = __uint_as_float(ph[j] & 0xFFFF0000u);
            pl[j] = cvt_pk(cf[2 * j] - h0, cf[2 * j + 1] - h1);
        }
        const bf16x8 bhi = pack4(ph[0], ph[1], ph[2], ph[3]);
        const bf16x8 blo = pack4(pl[0], pl[1], pl[2], pl[3]);
#pragma unroll
        for (int m = 0; m < 4; ++m) {
            ac[m] = __builtin_amdgcn_mfma_f32_16x16x32_bf16(wh[m], bhi, ac[m], 0, 0, 0);
            ac[m] = __builtin_amdgcn_mfma_f32_16x16x32_bf16(wh[m], blo, ac[m], 0, 0, 0);
            ac[m] = __builtin_amdgcn_mfma_f32_16x16x32_bf16(wl[m], bhi, ac[m], 0, 0, 0);
        }
    };

    bf16x8 WH0[4], WO0[4], WH1[4], WO1[4], WH2[4], WO2[4];

    // prologue FIFO: st0(4) W0(8) st1(4) W1(8) st2(4) = 28
    stage_x(0, sp0); SB0();
    loadW(0, WH0, WO0); SB0();
    stage_x(1, sp1); SB0();
    loadW(1, WH1, WO1); SB0();
    stage_x(2, sp2); SB0();

    // ITER(s): vmcnt(VM) drains {st(s),W(s)}; read slot s%3; fence; issue
    // W(s+2)->buf (s+2)%3 and st(s+3)->slot s%3; MFMA with W buf s%3.
#define ITER(s, nsl, nwl, VM, DOW, DOS)                                   \
    do {                                                                  \
        asm volatile("s_waitcnt vmcnt(" #VM ")" ::: "memory"); SB0();     \
        f32x4 va0, vb0, va1, vb1;                                         \
        readx(sp##nsl, va0, vb0, va1, vb1); SB0();                        \
        asm volatile("s_waitcnt lgkmcnt(0)" ::: "memory"); SB0();         \
        if (DOW) loadW((s) + 2, WH##nwl, WO##nwl);                        \
        SB0();                                                            \
        if (DOS) stage_x((s) + 3, sp##nsl);                               \
        SB0();                                                            \
        domfma(va0, vb0, WH##nsl, WO##nsl, a0);                           \
        domfma(va1, vb1, WH##nsl, WO##nsl, a1);                           \
    } while (0)

    ITER(0, 0, 2, 16, 1, 1);  ITER(1, 1, 0, 16, 1, 1);
    ITER(2, 2, 1, 16, 1, 1);  ITER(3, 0, 2, 16, 1, 1);
    ITER(4, 1, 0, 16, 1, 1);  ITER(5, 2, 1, 16, 1, 1);
    ITER(6, 0, 2, 16, 1, 1);  ITER(7, 1, 0, 16, 1, 1);
    ITER(8, 2, 1, 16, 1, 1);  ITER(9, 0, 2, 16, 1, 1);
    ITER(10, 1, 0, 16, 1, 1); ITER(11, 2, 1, 16, 1, 1);
    ITER(12, 0, 2, 16, 1, 1);               // loads W14->buf2, stages st15->slot0
    ITER(13, 1, 0, 16, 1, 0);               // loads W15->buf0, no stage
    ITER(14, 2, 0, 12, 0, 0);               // DOW=0: WH0 paste valid, unused
    ITER(15, 0, 0, 0, 0, 0);
#undef ITER

    // ---- 4-way K reduce through arena overlay (stride 36, 32 f/lane) -----
    __syncthreads();
    if (q != 0) {
        float* p = arena + (size_t)(q - 1) * 2304 + lane * 36;
#pragma unroll
        for (int m = 0; m < 4; ++m) {
            *(f32x4*)(p + m * 4) = a0[m];
            *(f32x4*)(p + 16 + m * 4) = a1[m];
        }
    }
    __syncthreads();
    if (q != 0) return;

#pragma unroll 1
    for (int qq = 0; qq < 3; ++qq) {
        const float* p = arena + (size_t)qq * 2304 + lane * 36;
#pragma unroll
        for (int m = 0; m < 4; ++m) {
            const f32x4 t0 = *(const f32x4*)(p + m * 4);
            const f32x4 t1 = *(const f32x4*)(p + 16 + m * 4);
            a0[m].x += t0.x; a0[m].y += t0.y; a0[m].z += t0.z; a0[m].w += t0.w;
            a1[m].x += t1.x; a1[m].y += t1.y; a1[m].z += t1.z; a1[m].w += t1.w;
        }
    }

    // ---- top-2 per tile (R13-verified): e = m*16 + (lane>>4)*4 + rr ------
    bins[lane] = 0.0f;
    const int col = lane & 15;
    const int erow = (lane >> 4) * 4;
    auto topk = [&](f32x4 (&r)[4], int tokbase) {
        float v1 = -3.4e38f, u1 = 0.0f, v2 = -3.4e38f, u2 = 0.0f;
        int i1 = 0x7fffffff, i2 = 0x7fffffff;
#pragma unroll
        for (int m = 0; m < 4; ++m)
#pragma unroll
            for (int rr = 0; rr < 4; ++rr) {
                const int e = m * 16 + erow + rr;
                const float u = r[m][rr];
                const float b = u - (loads[e] - 0.015625f) * 2.0f;
                if ((b > v1) || (b == v1 && e < i1)) {
                    v2 = v1; u2 = u1; i2 = i1;
                    v1 = b;  u1 = u;  i1 = e;
                } else if ((b > v2) || (b == v2 && e < i2)) {
                    v2 = b; u2 = u; i2 = e;
                }
            }
#pragma unroll
        for (int s = 0; s < 2; ++s) {
            const int mask = 16 << s;
            const float ov1 = __shfl_xor(v1, mask), ou1 = __shfl_xor(u1, mask);
            const float ov2 = __shfl_xor(v2, mask), ou2 = __shfl_xor(u2, mask);
            const int oi1 = __shfl_xor(i1, mask), oi2 = __shfl_xor(i2, mask);
            if ((ov1 > v1) || (ov1 == v1 && oi1 < i1)) {
                if ((v1 > ov2) || (v1 == ov2 && i1 < oi2)) { v2 = v1; u2 = u1; i2 = i1; }
                else                                        { v2 = ov2; u2 = ou2; i2 = oi2; }
                v1 = ov1; u1 = ou1; i1 = oi1;
            } else if ((ov1 > v2) || (ov1 == v2 && oi1 < i2)) {
                v2 = ov1; u2 = ou1; i2 = oi1;
            }
        }
        if (lane < 16) {
            const int tok = tokbase + col;
            const float mx = fmaxf(u1, u2);
            const float e1 = __expf(u1 - mx), e2 = __expf(u2 - mx);
            const float w1 = e1 / (e1 + e2), w2 = e2 / (e1 + e2);
            *(float2*)(out + 2 * tok) = make_float2(w1, w2);
            *(float2*)(out + 2 * TT + 2 * tok) = make_float2((float)i1, (float)i2);
            atomicAdd(&bins[i1], w1);
            atomicAdd(&bins[i2], w2);
        }
    };
    topk(a0, tb * 32);
    topk(a1, tb * 32 + 16);

    binpart[(size_t)tb * 64 + lane] = bins[lane];
}

// ---------------------------------------------------------------------------
// Merged finalize: 1 block x 1024 thr sums [512][64] rows (fixed order) + EMA.
__global__ __launch_bounds__(1024)
void finalize(const float* __restrict__ binpart, const float* __restrict__ loads,
              float* __restrict__ out) {
    __shared__ float p[16][64];
    const int e = threadIdx.x & 63, sub = threadIdx.x >> 6;  // 0..15
    float s = 0.0f;
#pragma unroll
    for (int r = 0; r < 32; ++r)
        s += binpart[(size_t)(sub * 32 + r) * 64 + e];
    p[sub][e] = s;
    __syncthreads();
    if (sub == 0) {
        float tot = 0.0f;
#pragma unroll
        for (int k = 0; k < 16; ++k) tot += p[k][e];
        out[4 * TT + e] = 0.9f * loads[e] + 0.1f * (tot * (1.0f / 16384.0f));
    }
}

// ---------------------------------------------------------------------------
extern "C" void kernel_launch(void* const* d_in, const int* in_sizes, int n_in,
                              void* d_out, int out_size, void* d_ws, size_t ws_size,
                              hipStream_t stream) {
    const float* x = (const float*)d_in[0];      // [16384, 2048]
    const float* wg = (const float*)d_in[1];     // [2048, 64]
    const float* loads = (const float*)d_in[2];  // [64]
    float* out = (float*)d_out;

    unsigned short* wpack = (unsigned short*)d_ws;               // 512 KB
    float* binpart = (float*)(wpack + (size_t)64 * 8 * 64 * 8);  // [512][64]

    hipLaunchKernelGGL(wconv, dim3(128), dim3(256), 0, stream, wg, wpack);
    hipLaunchKernelGGL(gate_fused, dim3(512), dim3(256), 0, stream,
                       x, wpack, loads, out, binpart);
    hipLaunchKernelGGL(finalize, dim3(1), dim3(1024), 0, stream,
                       binpart, loads, out);
}